// Round 3
// baseline (99.069 us; speedup 1.0000x reference)
//
#include <hip/hip_runtime.h>
#include <math.h>

// Problem constants (fixed by the reference file)
#define NPOINTS   8192
#define NDIM      64
#define TILE      128          // pairwise output tile per block
#define NT2       64           // NPOINTS / TILE
#define NBLK      2080         // NT2*(NT2+1)/2 triangle tiles
#define NGRP      512          // NPOINTS / 16 row-groups (prep blocks)

// ws dword/float layout:
//  [0, 262144)        W16f  : W as bf16 in MFMA-fragment order
//  [262144, 393216)   W8    : W as fp8 e4m3, packed 4/dword (8192 rows x 16 dwords)
//  [393216, 401408)   sq    : row squared norms (fp32 exact)
//  [401408, 403488)   partA : per-tile partials of sum 1/(1+d2) over a<b  (2080)
//  [403488, 407584)   a1p   : per-pair-job partials of sum pij*log(pij*(64+d2))
//  [407584, 411680)   a3p   : per-pair-job partials of sum pij
#define WS_W16   0
#define WS_W8    262144
#define WS_SQ    393216
#define WS_PARTA 401408
#define WS_A1P   403488
#define WS_A3P   407584

typedef __attribute__((ext_vector_type(8))) short bf16x8;   // 8 bf16 = 4 VGPRs (MFMA A/B frag)
typedef __attribute__((ext_vector_type(4))) float f32x4;    // MFMA C/D frag
typedef __attribute__((ext_vector_type(2))) float f32x2;

__device__ inline unsigned f2bf_pk(float lo, float hi) {    // pack 2 fp32 -> 2 bf16 (RNE)
    unsigned ul = __float_as_uint(lo), uh = __float_as_uint(hi);
    ul += 0x7FFFu + ((ul >> 16) & 1u);
    uh += 0x7FFFu + ((uh >> 16) & 1u);
    return (ul >> 16) | (uh & 0xFFFF0000u);
}
template <bool HI>
__device__ inline f32x2 cvt2(unsigned dw) {                 // 2 fp8 e4m3 -> 2 fp32 (HW cvt)
    return __builtin_amdgcn_cvt_pk_f32_fp8((int)dw, HI);    // word-sel must be constexpr
}
__device__ inline void sqacc(f32x2& s, unsigned a, unsigned b) {  // s += (deq(a)-deq(b))^2
    f32x2 dl = cvt2<false>(a) - cvt2<false>(b);
    f32x2 dh = cvt2<true >(a) - cvt2<true >(b);
    s += dl * dl;
    s += dh * dh;
}
__device__ inline float d2_16(const uint4 x[4], const uint4 y[4]) {  // ||xi-xj||^2 from fp8 rows
    f32x2 s2 = {0.f, 0.f};
    #pragma unroll
    for (int k = 0; k < 4; ++k) {
        sqacc(s2, x[k].x, y[k].x); sqacc(s2, x[k].y, y[k].y);
        sqacc(s2, x[k].z, y[k].z); sqacc(s2, x[k].w, y[k].w);
    }
    return s2.x + s2.y;
}

// One block per 16-row group g: emits (1) W16f fragment-order bf16, (2) exact
// fp32 row norms, (3) fp8 rows for the pair path. All loads/stores coalesced.
__global__ __launch_bounds__(256) void prep_kernel(const float* __restrict__ W,
                                                   float* __restrict__ sq,
                                                   unsigned* __restrict__ W16f,
                                                   unsigned* __restrict__ W8) {
    int g = blockIdx.x;
    int t = threadIdx.x;

    // ---- (1) fragment-order bf16: thread t -> (h, L, dpair), 4 floats -> uint2
    {
        int h = t >> 7, L = (t >> 1) & 63, dp = t & 1;
        int row = g * 16 + (L & 15), quad = L >> 4;
        float4 v = *(const float4*)(W + row * NDIM + h * 32 + quad * 8 + dp * 4);
        uint2 o;
        o.x = f2bf_pk(v.x, v.y);
        o.y = f2bf_pk(v.z, v.w);
        *(uint2*)(W16f + ((g * 2 + h) * 256 + L * 4 + dp * 2)) = o;
    }
    // ---- (2) exact row norms: thread t -> row r=t>>4, slice s=t&15 (4 elems)
    {
        int r = t >> 4, s = t & 15;
        float4 v = *(const float4*)(W + (g * 16 + r) * NDIM + s * 4);
        float p = v.x * v.x + v.y * v.y + v.z * v.z + v.w * v.w;
        p += __shfl_xor(p, 1, 64);
        p += __shfl_xor(p, 2, 64);
        p += __shfl_xor(p, 4, 64);
        p += __shfl_xor(p, 8, 64);
        if (s == 0) sq[g * 16 + r] = p;
    }
    // ---- (3) fp8 rows: thread t -> row t>>4, dword t&15
    {
        int r = g * 16 + (t >> 4), d = t & 15;
        float4 x = *(const float4*)(W + r * NDIM + d * 4);
        int lo = __builtin_amdgcn_cvt_pk_fp8_f32(x.x, x.y, 0, false);
        int dw = __builtin_amdgcn_cvt_pk_fp8_f32(x.z, x.w, lo, true);
        W8[r * 16 + d] = (unsigned)dw;
    }
}

// Standalone pair kernel, 2 pairs per thread (512/block): amortizes index-load
// latency and wave reduction over 2x work; 16 outstanding 16B gathers/thread.
// Lean VGPR standalone compile keeps all 1024 blocks co-resident in one shot
// (round-2 lesson: fusing with the MFMA tile path forced VGPR=100 on pair
// blocks and cost ~6 us net; the split version is the proven-fast structure).
__global__ __launch_bounds__(256) void pair_kernel(const unsigned* __restrict__ W8,
                                                   const float* __restrict__ pij,
                                                   const int* __restrict__ ii,
                                                   const int* __restrict__ jj,
                                                   int nb,
                                                   float* __restrict__ a1p,
                                                   float* __restrict__ a3p) {
    int t = threadIdx.x;
    int job = blockIdx.x;
    int p1 = job * 512 + t;
    int p2 = p1 + 256;
    bool v1 = p1 < nb, v2 = p2 < nb;
    int i1 = 0, j1 = 0, i2 = 0, j2 = 0;
    float q1 = 0.f, q2 = 0.f;
    if (v1) { i1 = ii[p1]; j1 = jj[p1]; q1 = pij[p1]; }
    if (v2) { i2 = ii[p2]; j2 = jj[p2]; q2 = pij[p2]; }
    const uint4* X1 = (const uint4*)(W8 + i1 * 16);
    const uint4* Y1 = (const uint4*)(W8 + j1 * 16);
    const uint4* X2 = (const uint4*)(W8 + i2 * 16);
    const uint4* Y2 = (const uint4*)(W8 + j2 * 16);
    uint4 xa[4], ya[4], xb[4], yb[4];            // 16 independent 16B gathers in flight
    #pragma unroll
    for (int k = 0; k < 4; ++k) xa[k] = X1[k];
    #pragma unroll
    for (int k = 0; k < 4; ++k) ya[k] = Y1[k];
    #pragma unroll
    for (int k = 0; k < 4; ++k) xb[k] = X2[k];
    #pragma unroll
    for (int k = 0; k < 4; ++k) yb[k] = Y2[k];
    float da = d2_16(xa, ya);                    // consumes first pair while second is in flight
    float db = d2_16(xb, yb);
    float a1 = 0.f, a3 = 0.f;
    if (v1) { a1  = q1 * __logf(q1 * ((float)NDIM + da)); a3  = q1; }
    if (v2) { a1 += q2 * __logf(q2 * ((float)NDIM + db)); a3 += q2; }
    #pragma unroll
    for (int m = 32; m >= 1; m >>= 1) {
        a1 += __shfl_xor(a1, m, 64);
        a3 += __shfl_xor(a3, m, 64);
    }
    __shared__ float red[8];
    if ((t & 63) == 0) { red[t >> 6] = a1; red[4 + (t >> 6)] = a3; }
    __syncthreads();
    if (t == 0) {
        a1p[job] = red[0] + red[1] + red[2] + red[3];
        a3p[job] = red[4] + red[5] + red[6] + red[7];
    }
}

// 128x128 triangle tile of the Cauchy partition via bf16 MFMA. Fragments load
// from the pre-swizzled W16f: one dwordx4 per lane, 64 lanes CONTIGUOUS (1 KB
// per instruction, 16 sequential cache lines) — no scattered line requests.
// Frag layouts (HW-verified): A/B = X[idx=lane&15][k=(lane>>4)*8+j];
// C/D row=(lane>>4)*4+reg, col=lane&15.
__global__ __launch_bounds__(256) void pairwise_kernel(const unsigned* __restrict__ W16f,
                                                       const float* __restrict__ sq,
                                                       float* __restrict__ partA) {
    int z = blockIdx.x;
    int t = threadIdx.x, w = t >> 6, lane = t & 63;
    int by = (int)((129.0f - sqrtf((float)(16641 - 8 * z))) * 0.5f);
    while (by * NT2 - by * (by - 1) / 2 > z) --by;
    while ((by + 1) * NT2 - (by + 1) * by / 2 <= z) ++by;
    int bx = by + (z - (by * NT2 - by * (by - 1) / 2));

    int wm = w >> 1, wn = w & 1, quad = lane >> 4, l15 = lane & 15;
    int a0 = by * TILE, b0 = bx * TILE;

    float4 base1[4];                 // 1 + sq[arow + tm*16 + 0..3]
    float  sqb[4];
    {
        int arow = a0 + wm * 64 + quad * 4;
        #pragma unroll
        for (int tm = 0; tm < 4; ++tm) {
            float4 v = *(const float4*)(sq + arow + tm * 16);
            base1[tm] = (float4){1.0f + v.x, 1.0f + v.y, 1.0f + v.z, 1.0f + v.w};
        }
        int bcol = b0 + wn * 64 + l15;
        #pragma unroll
        for (int tn = 0; tn < 4; ++tn) sqb[tn] = sq[bcol + tn * 16];
    }

    f32x4 acc[4][4];
    #pragma unroll
    for (int i = 0; i < 4; ++i)
        #pragma unroll
        for (int j = 0; j < 4; ++j) acc[i][j] = (f32x4){0.f, 0.f, 0.f, 0.f};

    int gA = (a0 >> 4) + wm * 4;     // A row-groups gA+tm; B row-groups gB+tn
    int gB = (b0 >> 4) + wn * 4;
    #pragma unroll
    for (int h = 0; h < 2; ++h) {    // two K=32 halves; 1 KB contiguous per frag
        bf16x8 af[4], bfr[4];
        #pragma unroll
        for (int tm = 0; tm < 4; ++tm)
            af[tm] = *(const bf16x8*)(W16f + (((gA + tm) * 2 + h) * 256 + lane * 4));
        #pragma unroll
        for (int tn = 0; tn < 4; ++tn)
            bfr[tn] = *(const bf16x8*)(W16f + (((gB + tn) * 2 + h) * 256 + lane * 4));
        #pragma unroll
        for (int tm = 0; tm < 4; ++tm)
            #pragma unroll
            for (int tn = 0; tn < 4; ++tn)
                acc[tm][tn] = __builtin_amdgcn_mfma_f32_16x16x32_bf16(af[tm], bfr[tn],
                                                                      acc[tm][tn], 0, 0, 0);
    }

    float ssum = 0.f;
    if (bx > by) {
        #pragma unroll
        for (int tn = 0; tn < 4; ++tn) {
            float c0 = sqb[tn];
            #pragma unroll
            for (int tm = 0; tm < 4; ++tm) {
                ssum += __builtin_amdgcn_rcpf(fmaf(acc[tm][tn][0], -2.0f, base1[tm].x + c0));
                ssum += __builtin_amdgcn_rcpf(fmaf(acc[tm][tn][1], -2.0f, base1[tm].y + c0));
                ssum += __builtin_amdgcn_rcpf(fmaf(acc[tm][tn][2], -2.0f, base1[tm].z + c0));
                ssum += __builtin_amdgcn_rcpf(fmaf(acc[tm][tn][3], -2.0f, base1[tm].w + c0));
            }
        }
    } else {                         // diagonal tile: strictly-upper only
        int quad4 = quad * 4;
        #pragma unroll
        for (int tn = 0; tn < 4; ++tn) {
            int cl = wn * 64 + tn * 16 + l15;
            float c0 = sqb[tn];
            float b4[4];
            #pragma unroll
            for (int tm = 0; tm < 4; ++tm) {
                b4[0] = base1[tm].x; b4[1] = base1[tm].y;
                b4[2] = base1[tm].z; b4[3] = base1[tm].w;
                #pragma unroll
                for (int r = 0; r < 4; ++r) {
                    int rl = wm * 64 + tm * 16 + quad4 + r;
                    float inv = __builtin_amdgcn_rcpf(fmaf(acc[tm][tn][r], -2.0f, b4[r] + c0));
                    ssum += (cl > rl) ? inv : 0.f;
                }
            }
        }
    }
    #pragma unroll
    for (int m = 32; m >= 1; m >>= 1) ssum += __shfl_xor(ssum, m, 64);
    __shared__ float wsum[4];
    if (lane == 0) wsum[w] = ssum;
    __syncthreads();
    if (t == 0) partA[z] = wsum[0] + wsum[1] + wsum[2] + wsum[3];
}

__global__ __launch_bounds__(256) void final_kernel(const float* __restrict__ partA,
                                                    const float* __restrict__ a1p,
                                                    const float* __restrict__ a3p,
                                                    int npb,
                                                    float* __restrict__ out) {
    __shared__ double r1[256], r2[256], r3[256];
    int t = threadIdx.x;
    double dpart = 0.0, d1 = 0.0, d3 = 0.0;
    for (int k = t; k < NBLK; k += 256) dpart += (double)partA[k];
    for (int k = t; k < npb; k += 256) { d1 += (double)a1p[k]; d3 += (double)a3p[k]; }
    r1[t] = dpart; r2[t] = d1; r3[t] = d3;
    __syncthreads();
    for (int s = 128; s >= 1; s >>= 1) {
        if (t < s) { r1[t] += r1[t + s]; r2[t] += r2[t + s]; r3[t] += r3[t + s]; }
        __syncthreads();
    }
    if (t == 0) {
        double part = 2.0 * r1[0];                 // sum over a<b, doubled; diagonal cancels -n
        out[0] = (float)(r2[0] + r3[0] * log(part));
    }
}

extern "C" void kernel_launch(void* const* d_in, const int* in_sizes, int n_in,
                              void* d_out, int out_size, void* d_ws, size_t ws_size,
                              hipStream_t stream) {
    const float* pij = (const float*)d_in[0];
    const int*   ii  = (const int*)d_in[1];
    const int*   jj  = (const int*)d_in[2];
    const float* W   = (const float*)d_in[3];
    float* out = (float*)d_out;
    float* ws  = (float*)d_ws;

    unsigned* W16f  = (unsigned*)ws + WS_W16;
    unsigned* W8    = (unsigned*)ws + WS_W8;
    float*    sqv   = ws + WS_SQ;
    float*    partA = ws + WS_PARTA;
    float*    a1p   = ws + WS_A1P;
    float*    a3p   = ws + WS_A3P;

    int nb   = in_sizes[0];           // number of sampled pairs (B)
    int npb2 = (nb + 511) / 512;      // pair-kernel blocks (1024 for B=524288)

    prep_kernel<<<NGRP, 256, 0, stream>>>(W, sqv, W16f, W8);
    pair_kernel<<<npb2, 256, 0, stream>>>(W8, pij, ii, jj, nb, a1p, a3p);
    pairwise_kernel<<<NBLK, 256, 0, stream>>>(W16f, sqv, partA);
    final_kernel<<<1, 256, 0, stream>>>(partA, a1p, a3p, npb2, out);
}

// Round 4
// 91.107 us; speedup vs baseline: 1.0874x; 1.0874x over previous
//
#include <hip/hip_runtime.h>
#include <math.h>

// Problem constants (fixed by the reference file)
#define NPOINTS   8192
#define NDIM      64
#define TILE      128          // pairwise output tile per block
#define NT2       64           // NPOINTS / TILE
#define NBLK      2080         // NT2*(NT2+1)/2 triangle tiles
#define NGRP      512          // NPOINTS / 16 row-groups (prep blocks)

// ws dword/float layout:
//  [0, 262144)        W16f  : W as bf16 in MFMA-fragment order
//  [262144, 393216)   W8    : W as fp8 e4m3, packed 4/dword (8192 rows x 16 dwords)
//  [393216, 401408)   sq    : row squared norms (fp32 exact)
//  [401408, 403488)   partA : per-tile partials of sum 1/(1+d2) over a<b  (2080)
//  [403488, 407584)   a1p   : per-pair-block partials of sum pij*log(pij*(64+d2))
//  [407584, 411680)   a3p   : per-pair-block partials of sum pij
#define WS_W16   0
#define WS_W8    262144
#define WS_SQ    393216
#define WS_PARTA 401408
#define WS_A1P   403488
#define WS_A3P   407584

typedef __attribute__((ext_vector_type(8))) short bf16x8;   // 8 bf16 = 4 VGPRs (MFMA A/B frag)
typedef __attribute__((ext_vector_type(4))) float f32x4;    // MFMA C/D frag
typedef __attribute__((ext_vector_type(2))) float f32x2;

__device__ inline unsigned f2bf_pk(float lo, float hi) {    // pack 2 fp32 -> 2 bf16 (RNE)
    unsigned ul = __float_as_uint(lo), uh = __float_as_uint(hi);
    ul += 0x7FFFu + ((ul >> 16) & 1u);
    uh += 0x7FFFu + ((uh >> 16) & 1u);
    return (ul >> 16) | (uh & 0xFFFF0000u);
}
template <bool HI>
__device__ inline f32x2 cvt2(unsigned dw) {                 // 2 fp8 e4m3 -> 2 fp32 (HW cvt)
    return __builtin_amdgcn_cvt_pk_f32_fp8((int)dw, HI);    // word-sel must be constexpr
}
__device__ inline void sqacc(f32x2& s, unsigned a, unsigned b) {  // s += (deq(a)-deq(b))^2
    f32x2 dl = cvt2<false>(a) - cvt2<false>(b);
    f32x2 dh = cvt2<true >(a) - cvt2<true >(b);
    s += dl * dl;
    s += dh * dh;
}

// One block per 16-row group g: emits (1) W16f fragment-order bf16, (2) exact
// fp32 row norms, (3) fp8 rows for the pair path. All loads/stores coalesced.
__global__ __launch_bounds__(256) void prep_kernel(const float* __restrict__ W,
                                                   float* __restrict__ sq,
                                                   unsigned* __restrict__ W16f,
                                                   unsigned* __restrict__ W8) {
    int g = blockIdx.x;
    int t = threadIdx.x;

    // ---- (1) fragment-order bf16: thread t -> (h, L, dpair), 4 floats -> uint2
    {
        int h = t >> 7, L = (t >> 1) & 63, dp = t & 1;
        int row = g * 16 + (L & 15), quad = L >> 4;
        float4 v = *(const float4*)(W + row * NDIM + h * 32 + quad * 8 + dp * 4);
        uint2 o;
        o.x = f2bf_pk(v.x, v.y);
        o.y = f2bf_pk(v.z, v.w);
        *(uint2*)(W16f + ((g * 2 + h) * 256 + L * 4 + dp * 2)) = o;
    }
    // ---- (2) exact row norms: thread t -> row r=t>>4, slice s=t&15 (4 elems)
    {
        int r = t >> 4, s = t & 15;
        float4 v = *(const float4*)(W + (g * 16 + r) * NDIM + s * 4);
        float p = v.x * v.x + v.y * v.y + v.z * v.z + v.w * v.w;
        p += __shfl_xor(p, 1, 64);
        p += __shfl_xor(p, 2, 64);
        p += __shfl_xor(p, 4, 64);
        p += __shfl_xor(p, 8, 64);
        if (s == 0) sq[g * 16 + r] = p;
    }
    // ---- (3) fp8 rows: thread t -> row t>>4, dword t&15
    {
        int r = g * 16 + (t >> 4), d = t & 15;
        float4 x = *(const float4*)(W + r * NDIM + d * 4);
        int lo = __builtin_amdgcn_cvt_pk_fp8_f32(x.x, x.y, 0, false);
        int dw = __builtin_amdgcn_cvt_pk_fp8_f32(x.z, x.w, lo, true);
        W8[r * 16 + d] = (unsigned)dw;
    }
}

// Pair kernel, quad-cooperative gather: 256 pairs/block (as baseline), but each
// fp8 row (64B = exactly one cache line) is loaded by 4 CONSECUTIVE lanes at
// 16B each -> the TA coalesces them into ONE line request. A wave gather
// instruction touches 16 distinct lines instead of 64 (round-3 theory: the
// old one-row-per-lane mapping was line-request-rate bound at ~1 line/cy/CU).
// Each quad computes its pair's partial d2 in-place (16 elems/lane) and
// reduces with 2 intra-quad shfl_xor. Instruction count and L2 traffic are
// unchanged; only the request pattern improves.
__global__ __launch_bounds__(256) void pair_kernel(const unsigned* __restrict__ W8,
                                                   const float* __restrict__ pij,
                                                   const int* __restrict__ ii,
                                                   const int* __restrict__ jj,
                                                   int nb,
                                                   float* __restrict__ a1p,
                                                   float* __restrict__ a3p) {
    int t = threadIdx.x;
    int w = t >> 6, lane = t & 63;
    int q = lane >> 2, c = lane & 3;           // pair slot within group; 16B chunk of row
    int base = blockIdx.x * 256 + w * 64 + q;  // pair index for group 0 (16 pairs/group)

    // ---- index loads for 4 groups (16 consecutive ints/wave-instr, 4-lane broadcast)
    int   ig[4], jg[4];
    float pg[4];
    #pragma unroll
    for (int g = 0; g < 4; ++g) {
        int p = base + g * 16;
        bool v = p < nb;
        ig[g] = v ? ii[p] : 0;
        jg[g] = v ? jj[p] : 0;
        pg[g] = v ? pij[p] : 0.f;              // pij >= 1e-6 when valid, 0 marks invalid
    }
    // ---- 8 independent coalesced gathers (4 lanes x 16B = one 64B line per row)
    uint4 xg[4], yg[4];
    #pragma unroll
    for (int g = 0; g < 4; ++g) xg[g] = *(const uint4*)(W8 + ig[g] * 16 + c * 4);
    #pragma unroll
    for (int g = 0; g < 4; ++g) yg[g] = *(const uint4*)(W8 + jg[g] * 16 + c * 4);

    float a1 = 0.f, a3 = 0.f;
    #pragma unroll
    for (int g = 0; g < 4; ++g) {
        f32x2 s2 = {0.f, 0.f};
        sqacc(s2, xg[g].x, yg[g].x);
        sqacc(s2, xg[g].y, yg[g].y);
        sqacc(s2, xg[g].z, yg[g].z);
        sqacc(s2, xg[g].w, yg[g].w);
        float s = s2.x + s2.y;                 // this lane's 16-dim partial
        s += __shfl_xor(s, 1, 64);
        s += __shfl_xor(s, 2, 64);             // full d2 in every lane of the quad
        float pv = pg[g];
        float t1 = pv * __logf(pv * ((float)NDIM + s));
        if (c == 0 && pv > 0.f) { a1 += t1; a3 += pv; }   // one contribution per pair
    }
    #pragma unroll
    for (int m = 32; m >= 1; m >>= 1) {
        a1 += __shfl_xor(a1, m, 64);
        a3 += __shfl_xor(a3, m, 64);
    }
    __shared__ float red[8];
    if ((t & 63) == 0) { red[t >> 6] = a1; red[4 + (t >> 6)] = a3; }
    __syncthreads();
    if (t == 0) {
        a1p[blockIdx.x] = red[0] + red[1] + red[2] + red[3];
        a3p[blockIdx.x] = red[4] + red[5] + red[6] + red[7];
    }
}

// 128x128 triangle tile of the Cauchy partition via bf16 MFMA. Fragments load
// from the pre-swizzled W16f: one dwordx4 per lane, 64 lanes CONTIGUOUS (1 KB
// per instruction, 16 sequential cache lines) — no scattered line requests.
// Frag layouts (HW-verified): A/B = X[idx=lane&15][k=(lane>>4)*8+j];
// C/D row=(lane>>4)*4+reg, col=lane&15.
__global__ __launch_bounds__(256) void pairwise_kernel(const unsigned* __restrict__ W16f,
                                                       const float* __restrict__ sq,
                                                       float* __restrict__ partA) {
    int z = blockIdx.x;
    int t = threadIdx.x, w = t >> 6, lane = t & 63;
    int by = (int)((129.0f - sqrtf((float)(16641 - 8 * z))) * 0.5f);
    while (by * NT2 - by * (by - 1) / 2 > z) --by;
    while ((by + 1) * NT2 - (by + 1) * by / 2 <= z) ++by;
    int bx = by + (z - (by * NT2 - by * (by - 1) / 2));

    int wm = w >> 1, wn = w & 1, quad = lane >> 4, l15 = lane & 15;
    int a0 = by * TILE, b0 = bx * TILE;

    float4 base1[4];                 // 1 + sq[arow + tm*16 + 0..3]
    float  sqb[4];
    {
        int arow = a0 + wm * 64 + quad * 4;
        #pragma unroll
        for (int tm = 0; tm < 4; ++tm) {
            float4 v = *(const float4*)(sq + arow + tm * 16);
            base1[tm] = (float4){1.0f + v.x, 1.0f + v.y, 1.0f + v.z, 1.0f + v.w};
        }
        int bcol = b0 + wn * 64 + l15;
        #pragma unroll
        for (int tn = 0; tn < 4; ++tn) sqb[tn] = sq[bcol + tn * 16];
    }

    f32x4 acc[4][4];
    #pragma unroll
    for (int i = 0; i < 4; ++i)
        #pragma unroll
        for (int j = 0; j < 4; ++j) acc[i][j] = (f32x4){0.f, 0.f, 0.f, 0.f};

    int gA = (a0 >> 4) + wm * 4;     // A row-groups gA+tm; B row-groups gB+tn
    int gB = (b0 >> 4) + wn * 4;
    #pragma unroll
    for (int h = 0; h < 2; ++h) {    // two K=32 halves; 1 KB contiguous per frag
        bf16x8 af[4], bfr[4];
        #pragma unroll
        for (int tm = 0; tm < 4; ++tm)
            af[tm] = *(const bf16x8*)(W16f + (((gA + tm) * 2 + h) * 256 + lane * 4));
        #pragma unroll
        for (int tn = 0; tn < 4; ++tn)
            bfr[tn] = *(const bf16x8*)(W16f + (((gB + tn) * 2 + h) * 256 + lane * 4));
        #pragma unroll
        for (int tm = 0; tm < 4; ++tm)
            #pragma unroll
            for (int tn = 0; tn < 4; ++tn)
                acc[tm][tn] = __builtin_amdgcn_mfma_f32_16x16x32_bf16(af[tm], bfr[tn],
                                                                      acc[tm][tn], 0, 0, 0);
    }

    float ssum = 0.f;
    if (bx > by) {
        #pragma unroll
        for (int tn = 0; tn < 4; ++tn) {
            float c0 = sqb[tn];
            #pragma unroll
            for (int tm = 0; tm < 4; ++tm) {
                ssum += __builtin_amdgcn_rcpf(fmaf(acc[tm][tn][0], -2.0f, base1[tm].x + c0));
                ssum += __builtin_amdgcn_rcpf(fmaf(acc[tm][tn][1], -2.0f, base1[tm].y + c0));
                ssum += __builtin_amdgcn_rcpf(fmaf(acc[tm][tn][2], -2.0f, base1[tm].z + c0));
                ssum += __builtin_amdgcn_rcpf(fmaf(acc[tm][tn][3], -2.0f, base1[tm].w + c0));
            }
        }
    } else {                         // diagonal tile: strictly-upper only
        int quad4 = quad * 4;
        #pragma unroll
        for (int tn = 0; tn < 4; ++tn) {
            int cl = wn * 64 + tn * 16 + l15;
            float c0 = sqb[tn];
            float b4[4];
            #pragma unroll
            for (int tm = 0; tm < 4; ++tm) {
                b4[0] = base1[tm].x; b4[1] = base1[tm].y;
                b4[2] = base1[tm].z; b4[3] = base1[tm].w;
                #pragma unroll
                for (int r = 0; r < 4; ++r) {
                    int rl = wm * 64 + tm * 16 + quad4 + r;
                    float inv = __builtin_amdgcn_rcpf(fmaf(acc[tm][tn][r], -2.0f, b4[r] + c0));
                    ssum += (cl > rl) ? inv : 0.f;
                }
            }
        }
    }
    #pragma unroll
    for (int m = 32; m >= 1; m >>= 1) ssum += __shfl_xor(ssum, m, 64);
    __shared__ float wsum[4];
    if (lane == 0) wsum[w] = ssum;
    __syncthreads();
    if (t == 0) partA[z] = wsum[0] + wsum[1] + wsum[2] + wsum[3];
}

__global__ __launch_bounds__(256) void final_kernel(const float* __restrict__ partA,
                                                    const float* __restrict__ a1p,
                                                    const float* __restrict__ a3p,
                                                    int npb,
                                                    float* __restrict__ out) {
    __shared__ double r1[256], r2[256], r3[256];
    int t = threadIdx.x;
    double dpart = 0.0, d1 = 0.0, d3 = 0.0;
    for (int k = t; k < NBLK; k += 256) dpart += (double)partA[k];
    for (int k = t; k < npb; k += 256) { d1 += (double)a1p[k]; d3 += (double)a3p[k]; }
    r1[t] = dpart; r2[t] = d1; r3[t] = d3;
    __syncthreads();
    for (int s = 128; s >= 1; s >>= 1) {
        if (t < s) { r1[t] += r1[t + s]; r2[t] += r2[t + s]; r3[t] += r3[t + s]; }
        __syncthreads();
    }
    if (t == 0) {
        double part = 2.0 * r1[0];                 // sum over a<b, doubled; diagonal cancels -n
        out[0] = (float)(r2[0] + r3[0] * log(part));
    }
}

extern "C" void kernel_launch(void* const* d_in, const int* in_sizes, int n_in,
                              void* d_out, int out_size, void* d_ws, size_t ws_size,
                              hipStream_t stream) {
    const float* pij = (const float*)d_in[0];
    const int*   ii  = (const int*)d_in[1];
    const int*   jj  = (const int*)d_in[2];
    const float* W   = (const float*)d_in[3];
    float* out = (float*)d_out;
    float* ws  = (float*)d_ws;

    unsigned* W16f  = (unsigned*)ws + WS_W16;
    unsigned* W8    = (unsigned*)ws + WS_W8;
    float*    sqv   = ws + WS_SQ;
    float*    partA = ws + WS_PARTA;
    float*    a1p   = ws + WS_A1P;
    float*    a3p   = ws + WS_A3P;

    int nb  = in_sizes[0];            // number of sampled pairs (B)
    int npb = (nb + 255) / 256;       // pair-kernel blocks (2048 for B=524288)

    prep_kernel<<<NGRP, 256, 0, stream>>>(W, sqv, W16f, W8);
    pair_kernel<<<npb, 256, 0, stream>>>(W8, pij, ii, jj, nb, a1p, a3p);
    pairwise_kernel<<<NBLK, 256, 0, stream>>>(W16f, sqv, partA);
    final_kernel<<<1, 256, 0, stream>>>(partA, a1p, a3p, npb, out);
}

// Round 5
// 90.816 us; speedup vs baseline: 1.0909x; 1.0032x over previous
//
#include <hip/hip_runtime.h>
#include <math.h>

// Problem constants (fixed by the reference file)
#define NPOINTS   8192
#define NDIM      64
#define TILE      128          // pairwise output tile per block
#define NT2       64           // NPOINTS / TILE
#define NBLK      2080         // NT2*(NT2+1)/2 triangle tiles
#define NGRP      512          // NPOINTS / 16 row-groups (prep blocks)

// ws dword/float layout:
//  [0, 262144)        W16f  : W as bf16 in MFMA-fragment order:
//                             chunk c = (rowgroup g)*2 + h  (g=row/16, h=K-half)
//                             dword addr = c*256 + lane*4 + d ; lane=quad*16+l15
//                             holds row g*16+l15, bf16 elems h*32+quad*8 .. +8
//  [262144, 393216)   W8    : W as fp8 e4m3, packed 4/dword (8192 rows x 16 dwords)
//  [393216, 401408)   sq    : row squared norms (fp32 exact)
//  [401408, 403488)   partA : per-tile partials of sum 1/(1+d2) over a<b  (2080)
//  [403488, 407584)   a1p   : per-pair-block partials of sum pij*log(pij*(64+d2))
//  [407584, 411680)   a3p   : per-pair-block partials of sum pij
#define WS_W16   0
#define WS_W8    262144
#define WS_SQ    393216
#define WS_PARTA 401408
#define WS_A1P   403488
#define WS_A3P   407584

typedef __attribute__((ext_vector_type(8))) short bf16x8;   // 8 bf16 = 4 VGPRs (MFMA A/B frag)
typedef __attribute__((ext_vector_type(4))) float f32x4;    // MFMA C/D frag
typedef __attribute__((ext_vector_type(2))) float f32x2;

__device__ inline unsigned f2bf_pk(float lo, float hi) {    // pack 2 fp32 -> 2 bf16 (RNE)
    unsigned ul = __float_as_uint(lo), uh = __float_as_uint(hi);
    ul += 0x7FFFu + ((ul >> 16) & 1u);
    uh += 0x7FFFu + ((uh >> 16) & 1u);
    return (ul >> 16) | (uh & 0xFFFF0000u);
}
template <bool HI>
__device__ inline f32x2 cvt2(unsigned dw) {                 // 2 fp8 e4m3 -> 2 fp32 (HW cvt)
    return __builtin_amdgcn_cvt_pk_f32_fp8((int)dw, HI);    // word-sel must be constexpr
}
__device__ inline void sqacc(f32x2& s, unsigned a, unsigned b) {  // s += (deq(a)-deq(b))^2
    f32x2 dl = cvt2<false>(a) - cvt2<false>(b);
    f32x2 dh = cvt2<true >(a) - cvt2<true >(b);
    s += dl * dl;
    s += dh * dh;
}

// One block per 16-row group g: emits (1) W16f fragment-order bf16, (2) exact
// fp32 row norms, (3) fp8 rows for the pair path. All loads/stores coalesced.
__global__ __launch_bounds__(256) void prep_kernel(const float* __restrict__ W,
                                                   float* __restrict__ sq,
                                                   unsigned* __restrict__ W16f,
                                                   unsigned* __restrict__ W8) {
    int g = blockIdx.x;
    int t = threadIdx.x;

    // ---- (1) fragment-order bf16: thread t -> (h, L, dpair), 4 floats -> uint2
    {
        int h = t >> 7, L = (t >> 1) & 63, dp = t & 1;
        int row = g * 16 + (L & 15), quad = L >> 4;
        float4 v = *(const float4*)(W + row * NDIM + h * 32 + quad * 8 + dp * 4);
        uint2 o;
        o.x = f2bf_pk(v.x, v.y);
        o.y = f2bf_pk(v.z, v.w);
        *(uint2*)(W16f + ((g * 2 + h) * 256 + L * 4 + dp * 2)) = o;
    }
    // ---- (2) exact row norms: thread t -> row r=t>>4, slice s=t&15 (4 elems)
    {
        int r = t >> 4, s = t & 15;
        float4 v = *(const float4*)(W + (g * 16 + r) * NDIM + s * 4);
        float p = v.x * v.x + v.y * v.y + v.z * v.z + v.w * v.w;
        p += __shfl_xor(p, 1, 64);
        p += __shfl_xor(p, 2, 64);
        p += __shfl_xor(p, 4, 64);
        p += __shfl_xor(p, 8, 64);
        if (s == 0) sq[g * 16 + r] = p;
    }
    // ---- (3) fp8 rows: thread t -> row t>>4, dword t&15
    {
        int r = g * 16 + (t >> 4), d = t & 15;
        float4 x = *(const float4*)(W + r * NDIM + d * 4);
        int lo = __builtin_amdgcn_cvt_pk_fp8_f32(x.x, x.y, 0, false);
        int dw = __builtin_amdgcn_cvt_pk_fp8_f32(x.z, x.w, lo, true);
        W8[r * 16 + d] = (unsigned)dw;
    }
}

// One THREAD per sampled pair, one shot: coalesced index load -> 8 independent
// dwordx4 gathers (both full fp8 rows) -> in-register decode/diff -> 1 log.
// R3/R4 lessons: 2 pairs/thread (-occupancy) costs +8.6us; quad-cooperative
// gather (4x fewer line requests) is neutral -> the kernel is latency-bound on
// the index->gather chain and fully hidden at 32 waves/CU. This mapping is the
// measured optimum.
__global__ __launch_bounds__(256) void pair_kernel(const unsigned* __restrict__ W8,
                                                   const float* __restrict__ pij,
                                                   const int* __restrict__ ii,
                                                   const int* __restrict__ jj,
                                                   int nb,
                                                   float* __restrict__ a1p,
                                                   float* __restrict__ a3p) {
    int t = threadIdx.x;
    int p = blockIdx.x * 256 + t;
    float a1 = 0.f, a3 = 0.f;
    if (p < nb) {
        int   i  = ii[p];
        int   j  = jj[p];
        float pv = pij[p];
        const uint4* X = (const uint4*)(W8 + i * 16);
        const uint4* Y = (const uint4*)(W8 + j * 16);
        uint4 x0 = X[0], x1 = X[1], x2 = X[2], x3 = X[3];   // 8 independent 16B loads
        uint4 y0 = Y[0], y1 = Y[1], y2 = Y[2], y3 = Y[3];
        f32x2 s2 = {0.f, 0.f};
        sqacc(s2, x0.x, y0.x); sqacc(s2, x0.y, y0.y);
        sqacc(s2, x0.z, y0.z); sqacc(s2, x0.w, y0.w);
        sqacc(s2, x1.x, y1.x); sqacc(s2, x1.y, y1.y);
        sqacc(s2, x1.z, y1.z); sqacc(s2, x1.w, y1.w);
        sqacc(s2, x2.x, y2.x); sqacc(s2, x2.y, y2.y);
        sqacc(s2, x2.z, y2.z); sqacc(s2, x2.w, y2.w);
        sqacc(s2, x3.x, y3.x); sqacc(s2, x3.y, y3.y);
        sqacc(s2, x3.z, y3.z); sqacc(s2, x3.w, y3.w);
        float v = s2.x + s2.y;                              // ||xi-xj||^2
        a1 = pv * __logf(pv * ((float)NDIM + v));
        a3 = pv;
    }
    #pragma unroll
    for (int m = 32; m >= 1; m >>= 1) {
        a1 += __shfl_xor(a1, m, 64);
        a3 += __shfl_xor(a3, m, 64);
    }
    __shared__ float red[8];
    if ((t & 63) == 0) { red[t >> 6] = a1; red[4 + (t >> 6)] = a3; }
    __syncthreads();
    if (t == 0) {
        a1p[blockIdx.x] = red[0] + red[1] + red[2] + red[3];
        a3p[blockIdx.x] = red[4] + red[5] + red[6] + red[7];
    }
}

// 128x128 triangle tile of the Cauchy partition via bf16 MFMA. Fragments load
// from the pre-swizzled W16f: one dwordx4 per lane, 64 lanes CONTIGUOUS (1 KB
// per instruction, 16 sequential cache lines) — no scattered line requests.
// Frag layouts (HW-verified): A/B = X[idx=lane&15][k=(lane>>4)*8+j];
// C/D row=(lane>>4)*4+reg, col=lane&15.
__global__ __launch_bounds__(256) void pairwise_kernel(const unsigned* __restrict__ W16f,
                                                       const float* __restrict__ sq,
                                                       float* __restrict__ partA) {
    int z = blockIdx.x;
    int t = threadIdx.x, w = t >> 6, lane = t & 63;
    int by = (int)((129.0f - sqrtf((float)(16641 - 8 * z))) * 0.5f);
    while (by * NT2 - by * (by - 1) / 2 > z) --by;
    while ((by + 1) * NT2 - (by + 1) * by / 2 <= z) ++by;
    int bx = by + (z - (by * NT2 - by * (by - 1) / 2));

    int wm = w >> 1, wn = w & 1, quad = lane >> 4, l15 = lane & 15;
    int a0 = by * TILE, b0 = bx * TILE;

    float4 base1[4];                 // 1 + sq[arow + tm*16 + 0..3]
    float  sqb[4];
    {
        int arow = a0 + wm * 64 + quad * 4;
        #pragma unroll
        for (int tm = 0; tm < 4; ++tm) {
            float4 v = *(const float4*)(sq + arow + tm * 16);
            base1[tm] = (float4){1.0f + v.x, 1.0f + v.y, 1.0f + v.z, 1.0f + v.w};
        }
        int bcol = b0 + wn * 64 + l15;
        #pragma unroll
        for (int tn = 0; tn < 4; ++tn) sqb[tn] = sq[bcol + tn * 16];
    }

    f32x4 acc[4][4];
    #pragma unroll
    for (int i = 0; i < 4; ++i)
        #pragma unroll
        for (int j = 0; j < 4; ++j) acc[i][j] = (f32x4){0.f, 0.f, 0.f, 0.f};

    int gA = (a0 >> 4) + wm * 4;     // A row-groups gA+tm; B row-groups gB+tn
    int gB = (b0 >> 4) + wn * 4;
    #pragma unroll
    for (int h = 0; h < 2; ++h) {    // two K=32 halves; 1 KB contiguous per frag
        bf16x8 af[4], bfr[4];
        #pragma unroll
        for (int tm = 0; tm < 4; ++tm)
            af[tm] = *(const bf16x8*)(W16f + (((gA + tm) * 2 + h) * 256 + lane * 4));
        #pragma unroll
        for (int tn = 0; tn < 4; ++tn)
            bfr[tn] = *(const bf16x8*)(W16f + (((gB + tn) * 2 + h) * 256 + lane * 4));
        #pragma unroll
        for (int tm = 0; tm < 4; ++tm)
            #pragma unroll
            for (int tn = 0; tn < 4; ++tn)
                acc[tm][tn] = __builtin_amdgcn_mfma_f32_16x16x32_bf16(af[tm], bfr[tn],
                                                                      acc[tm][tn], 0, 0, 0);
    }

    float ssum = 0.f;
    if (bx > by) {
        #pragma unroll
        for (int tn = 0; tn < 4; ++tn) {
            float c0 = sqb[tn];
            #pragma unroll
            for (int tm = 0; tm < 4; ++tm) {
                ssum += __builtin_amdgcn_rcpf(fmaf(acc[tm][tn][0], -2.0f, base1[tm].x + c0));
                ssum += __builtin_amdgcn_rcpf(fmaf(acc[tm][tn][1], -2.0f, base1[tm].y + c0));
                ssum += __builtin_amdgcn_rcpf(fmaf(acc[tm][tn][2], -2.0f, base1[tm].z + c0));
                ssum += __builtin_amdgcn_rcpf(fmaf(acc[tm][tn][3], -2.0f, base1[tm].w + c0));
            }
        }
    } else {                         // diagonal tile: strictly-upper only
        int quad4 = quad * 4;
        #pragma unroll
        for (int tn = 0; tn < 4; ++tn) {
            int cl = wn * 64 + tn * 16 + l15;
            float c0 = sqb[tn];
            float b4[4];
            #pragma unroll
            for (int tm = 0; tm < 4; ++tm) {
                b4[0] = base1[tm].x; b4[1] = base1[tm].y;
                b4[2] = base1[tm].z; b4[3] = base1[tm].w;
                #pragma unroll
                for (int r = 0; r < 4; ++r) {
                    int rl = wm * 64 + tm * 16 + quad4 + r;
                    float inv = __builtin_amdgcn_rcpf(fmaf(acc[tm][tn][r], -2.0f, b4[r] + c0));
                    ssum += (cl > rl) ? inv : 0.f;
                }
            }
        }
    }
    #pragma unroll
    for (int m = 32; m >= 1; m >>= 1) ssum += __shfl_xor(ssum, m, 64);
    __shared__ float wsum[4];
    if (lane == 0) wsum[w] = ssum;
    __syncthreads();
    if (t == 0) partA[z] = wsum[0] + wsum[1] + wsum[2] + wsum[3];
}

__global__ __launch_bounds__(256) void final_kernel(const float* __restrict__ partA,
                                                    const float* __restrict__ a1p,
                                                    const float* __restrict__ a3p,
                                                    int npb,
                                                    float* __restrict__ out) {
    __shared__ double r1[256], r2[256], r3[256];
    int t = threadIdx.x;
    double dpart = 0.0, d1 = 0.0, d3 = 0.0;
    for (int k = t; k < NBLK; k += 256) dpart += (double)partA[k];
    for (int k = t; k < npb; k += 256) { d1 += (double)a1p[k]; d3 += (double)a3p[k]; }
    r1[t] = dpart; r2[t] = d1; r3[t] = d3;
    __syncthreads();
    for (int s = 128; s >= 1; s >>= 1) {
        if (t < s) { r1[t] += r1[t + s]; r2[t] += r2[t + s]; r3[t] += r3[t + s]; }
        __syncthreads();
    }
    if (t == 0) {
        double part = 2.0 * r1[0];                 // sum over a<b, doubled; diagonal cancels -n
        out[0] = (float)(r2[0] + r3[0] * log(part));
    }
}

extern "C" void kernel_launch(void* const* d_in, const int* in_sizes, int n_in,
                              void* d_out, int out_size, void* d_ws, size_t ws_size,
                              hipStream_t stream) {
    const float* pij = (const float*)d_in[0];
    const int*   ii  = (const int*)d_in[1];
    const int*   jj  = (const int*)d_in[2];
    const float* W   = (const float*)d_in[3];
    float* out = (float*)d_out;
    float* ws  = (float*)d_ws;

    unsigned* W16f  = (unsigned*)ws + WS_W16;
    unsigned* W8    = (unsigned*)ws + WS_W8;
    float*    sqv   = ws + WS_SQ;
    float*    partA = ws + WS_PARTA;
    float*    a1p   = ws + WS_A1P;
    float*    a3p   = ws + WS_A3P;

    int nb  = in_sizes[0];            // number of sampled pairs (B)
    int npb = (nb + 255) / 256;       // pair-kernel blocks (2048 for B=524288)

    prep_kernel<<<NGRP, 256, 0, stream>>>(W, sqv, W16f, W8);
    pair_kernel<<<npb, 256, 0, stream>>>(W8, pij, ii, jj, nb, a1p, a3p);
    pairwise_kernel<<<NBLK, 256, 0, stream>>>(W16f, sqv, partA);
    final_kernel<<<1, 256, 0, stream>>>(partA, a1p, a3p, npb, out);
}